// Round 9
// baseline (165.600 us; speedup 1.0000x reference)
//
#include <hip/hip_runtime.h>
#include <hip/hip_bf16.h>
#include <stdint.h>

// ---------- types ----------
typedef __bf16 bf16x8 __attribute__((ext_vector_type(8)));
typedef __bf16 bf16x4 __attribute__((ext_vector_type(4)));
typedef float  f32x4  __attribute__((ext_vector_type(4)));
typedef float  f32x16 __attribute__((ext_vector_type(16)));

__device__ __forceinline__ unsigned short f2bf(float f) {
    unsigned u = __builtin_bit_cast(unsigned, f);
    u += 0x7fffu + ((u >> 16) & 1u);   // RNE
    return (unsigned short)(u >> 16);
}

__device__ __forceinline__ void gload16(const void* g, void* l) {
    __builtin_amdgcn_global_load_lds((const __attribute__((address_space(1))) void*)g,
                                     (__attribute__((address_space(3))) void*)l, 16, 0, 0);
}

// ---------- fused fp32 -> bf16 convert for x, w_qkv, w_proj (one launch) ----------
#define XN  4194304   // 4096*1024
#define WQN 3145728   // 3072*1024
#define WPN 1048576   // 1024*1024
__global__ void cvt_all(const float* __restrict__ x, const float* __restrict__ wq,
                        const float* __restrict__ wp,
                        unsigned short* __restrict__ xb, unsigned short* __restrict__ wqb,
                        unsigned short* __restrict__ wpb) {
    int i = (blockIdx.x * blockDim.x + threadIdx.x) * 4;
    const float* src; unsigned short* dst; int off;
    if (i < XN)            { src = x;  dst = xb;  off = i; }
    else if (i < XN + WQN) { src = wq; dst = wqb; off = i - XN; }
    else                   { src = wp; dst = wpb; off = i - XN - WQN; }
    float4 v = *(const float4*)(src + off);
    ushort4 o;
    o.x = f2bf(v.x); o.y = f2bf(v.y); o.z = f2bf(v.z); o.w = f2bf(v.w);
    *(ushort4*)(dst + off) = o;
}

// ---------- GEMM C = A * B^T  (A [M,K] row-major bf16, B [N,K] row-major bf16) ----------
// 128x128 tile, BK=64, 4 waves 2x2, global_load_lds width-16 staging, XCD-swizzled grid.
#define BM 128
#define BN 128
#define BKK 64

template<int MODE>
__global__ void gemm_bt(const unsigned short* __restrict__ A,
                        const unsigned short* __restrict__ Bm,
                        int M, int N, int K,
                        float* __restrict__ Cf,
                        unsigned short* __restrict__ Qo,
                        unsigned short* __restrict__ Ko,
                        unsigned short* __restrict__ Vo) {
    __shared__ __align__(16) unsigned short Als[BM * BKK];
    __shared__ __align__(16) unsigned short Bls[BN * BKK];

    const int tid  = threadIdx.x;
    const int lane = tid & 63;
    const int wave = tid >> 6;
    const int wm = wave >> 1, wn = wave & 1;
    // T1: XCD-aware swizzle (grid size divisible by 8 for both GEMMs)
    const int nwg = gridDim.x * gridDim.y;
    const int lid = blockIdx.y * gridDim.x + blockIdx.x;
    const int cpx = nwg >> 3;
    const int swz = (lid & 7) * cpx + (lid >> 3);
    const int m0 = (swz / gridDim.x) * BM, n0 = (swz % gridDim.x) * BN;
    const int l16 = lane & 15, lg = lane >> 4;

    f32x4 acc[4][4];
#pragma unroll
    for (int i = 0; i < 4; i++)
#pragma unroll
        for (int j = 0; j < 4; j++) acc[i][j] = f32x4{0.f, 0.f, 0.f, 0.f};

    const int r0 = tid >> 3;   // row 0..31
    const int c8 = tid & 7;    // 16B chunk

    for (int k0 = 0; k0 < K; k0 += BKK) {
        __syncthreads();
#pragma unroll
        for (int i = 0; i < 4; i++) {
            gload16(A  + (size_t)(m0 + r0 + i * 32) * K + k0 + c8 * 8,
                    Als + i * 2048 + wave * 512);
            gload16(Bm + (size_t)(n0 + r0 + i * 32) * K + k0 + c8 * 8,
                    Bls + i * 2048 + wave * 512);
        }
        __syncthreads();
#pragma unroll
        for (int ks = 0; ks < 2; ++ks) {
            const int koff = ks * 32 + lg * 8;
            bf16x8 af[4], bfv[4];
#pragma unroll
            for (int mf = 0; mf < 4; ++mf)
                af[mf] = *(const bf16x8*)(Als + (wm * 64 + mf * 16 + l16) * BKK + koff);
#pragma unroll
            for (int nf = 0; nf < 4; ++nf)
                bfv[nf] = *(const bf16x8*)(Bls + (wn * 64 + nf * 16 + l16) * BKK + koff);
#pragma unroll
            for (int mf = 0; mf < 4; ++mf)
#pragma unroll
                for (int nf = 0; nf < 4; ++nf)
                    acc[mf][nf] = __builtin_amdgcn_mfma_f32_16x16x32_bf16(af[mf], bfv[nf], acc[mf][nf], 0, 0, 0);
        }
    }

#pragma unroll
    for (int mf = 0; mf < 4; ++mf) {
        int gm = m0 + wm * 64 + mf * 16 + (lg << 2);
#pragma unroll
        for (int nf = 0; nf < 4; ++nf) {
            int gn = n0 + wn * 64 + nf * 16 + l16;
            if (MODE == 0) {
                int which = gn >> 10;
                int rem = gn & 1023;
                int h = rem >> 6, d = rem & 63;
                unsigned short* dst = (which == 0) ? Qo : (which == 1) ? Ko : Vo;
                float s = (which == 0) ? 0.180336884f : 1.0f;   // 0.125 * log2(e) for Q
#pragma unroll
                for (int j = 0; j < 4; j++) {
                    int m = gm + j;
                    int b = m >> 11, t = m & 2047;
                    dst[((size_t)((b << 4) + h) * 2048 + t) * 64 + d] = f2bf(acc[mf][nf][j] * s);
                }
            } else {
#pragma unroll
                for (int j = 0; j < 4; j++)
                    Cf[(size_t)(gm + j) * N + gn] = acc[mf][nf][j];
            }
        }
    }
}

// ---------- causal flash attention (32x32 swapped MFMA, in-register softmax) ----------
// 1D grid of 512 blocks SORTED LONGEST-FIRST: bid -> qt = 15-(bid>>5), bh = bid&31.
// QBLK=128: 4 waves x 32 q-rows. 32x32x16 MFMA halves LDS bytes per FLOP vs 16x16x32.
// NO launch_bounds: R8's (256,4) capped VGPR at 128 -> scratch spill (+25MB WRITE_SIZE).
// Grid caps residency at 2 blocks/CU anyway; let the allocator keep ~170 VGPR, no spill.
__global__ void attn_fwd(const unsigned short* __restrict__ Q,
                         const unsigned short* __restrict__ Kg,
                         const unsigned short* __restrict__ V,
                         unsigned short* __restrict__ O) {
    __shared__ __align__(16) unsigned short Kls[64 * 64];
    __shared__ __align__(16) unsigned short Vt[64 * 64];    // [dim][key], swizzled
    __shared__ __align__(16) unsigned short Pls[4][32 * 64];

    const int tid = threadIdx.x, lane = tid & 63, wv = tid >> 6;
    const int l31 = lane & 31, b5 = lane >> 5;
    const int bid = blockIdx.x;
    const int qt = 15 - (bid >> 5);           // q-tile (128 rows), longest first
    const int bh = bid & 31;
    const size_t base = (size_t)bh * 2048 * 64;
    const unsigned short* Qp = Q + base;
    const unsigned short* Kp = Kg + base;
    const unsigned short* Vp = V + base;
    const int sr  = tid >> 3;   // staging row 0..31
    const int sc8 = tid & 7;    // staging 16B chunk
    const int b = bh >> 4, h = bh & 15;

    const int q0 = qt * 128;
    const int ntblk = 2 * qt + 2;             // KV tiles this block stages
    const int qrow = q0 + wv * 32 + l31;      // this lane's q-row
    const int qtw  = (q0 + wv * 32) >> 6;     // wave's diagonal KV-tile index
    const int pswz = ((l31 ^ (l31 >> 3)) & 7) << 3;

    // Q fragments in regs (pre-scaled by 0.125*log2e): Q[d = m*16 + b5*8 + j][q = l31]
    bf16x8 qf[4];
#pragma unroll
    for (int m = 0; m < 4; m++)
        qf[m] = *(const bf16x8*)(Qp + (size_t)qrow * 64 + m * 16 + b5 * 8);

    float mst = -INFINITY, lsum = 0.f;
    f32x16 oacc0, oacc1;
#pragma unroll
    for (int r = 0; r < 16; r++) { oacc0[r] = 0.f; oacc1[r] = 0.f; }

    // prefetch tile 0 (two 16B chunks of K and V per thread)
    uint4 kreg[2], vreg[2];
#pragma unroll
    for (int i = 0; i < 2; i++) {
        int r = sr + i * 32;
        kreg[i] = *(const uint4*)(Kp + (size_t)r * 64 + sc8 * 8);
        vreg[i] = *(const uint4*)(Vp + (size_t)r * 64 + sc8 * 8);
    }

    for (int kt = 0; kt < ntblk; ++kt) {
        __syncthreads();
#pragma unroll
        for (int i = 0; i < 2; i++) {
            int r = sr + i * 32;
            *(uint4*)(Kls + r * 64 + ((sc8 ^ (r & 7)) << 3)) = kreg[i];
            const unsigned short* pv = (const unsigned short*)&vreg[i];
#pragma unroll
            for (int j = 0; j < 8; j++) {
                int d = sc8 * 8 + j;
                Vt[d * 64 + (r ^ ((j ^ sc8) << 3))] = pv[j];
            }
        }
        __syncthreads();
        if (kt + 1 < ntblk) {
#pragma unroll
            for (int i = 0; i < 2; i++) {
                int r = sr + i * 32;
                kreg[i] = *(const uint4*)(Kp + (size_t)((kt + 1) * 64 + r) * 64 + sc8 * 8);
                vreg[i] = *(const uint4*)(Vp + (size_t)((kt + 1) * 64 + r) * 64 + sc8 * 8);
            }
        }

        if (kt > qtw) continue;   // fully masked for this wave

        // S^T = K Q^T : two key-tiles of 32, k-dim = d (4 steps of 16)
        f32x16 s0, s1;
#pragma unroll
        for (int r = 0; r < 16; r++) { s0[r] = 0.f; s1[r] = 0.f; }
#pragma unroll
        for (int m = 0; m < 4; m++) {
            const int koff = m * 16 + b5 * 8;
            int k0i = l31;
            int k1i = 32 + l31;
            bf16x8 kf0 = *(const bf16x8*)(Kls + k0i * 64 + (koff ^ ((k0i & 7) << 3)));
            bf16x8 kf1 = *(const bf16x8*)(Kls + k1i * 64 + (koff ^ ((k1i & 7) << 3)));
            s0 = __builtin_amdgcn_mfma_f32_32x32x16_bf16(kf0, qf[m], s0, 0, 0, 0);
            s1 = __builtin_amdgcn_mfma_f32_32x32x16_bf16(kf1, qf[m], s1, 0, 0, 0);
        }

        // causal mask on wave's diagonal tile
        if (kt == qtw) {
#pragma unroll
            for (int r = 0; r < 16; r++) {
                int keyg = kt * 64 + (r & 3) + 8 * (r >> 2) + 4 * b5;
                if (keyg > qrow)      s0[r] = -INFINITY;
                if (keyg + 32 > qrow) s1[r] = -INFINITY;
            }
        }

        // row max (lane-local 32 + one cross-half shfl), defer-max rescale (T13)
        float xm = fmaxf(s0[0], s1[0]);
#pragma unroll
        for (int r = 1; r < 16; r++) xm = fmaxf(xm, fmaxf(s0[r], s1[r]));
        float x = fmaxf(xm, __shfl_xor(xm, 32));
        if (!__all(x - mst <= 8.0f)) {
            float mnew  = fmaxf(mst, x);
            float alpha = __builtin_amdgcn_exp2f(mst - mnew);
            mst = mnew;
            lsum *= alpha;
#pragma unroll
            for (int r = 0; r < 16; r++) { oacc0[r] *= alpha; oacc1[r] *= alpha; }
        }

        float ra = 0.f, rb = 0.f;
#pragma unroll
        for (int r = 0; r < 16; r++) {
            s0[r] = __builtin_amdgcn_exp2f(s0[r] - mst);
            s1[r] = __builtin_amdgcn_exp2f(s1[r] - mst);
            ra += s0[r]; rb += s1[r];
        }
        float rs = ra + rb;
        rs += __shfl_xor(rs, 32);
        lsum += rs;

        // P -> LDS: row = q (l31); chunk (c*4+g), half 4*b5; swizzled by pswz
#pragma unroll
        for (int g = 0; g < 4; g++) {
            bf16x4 pk;
#pragma unroll
            for (int jj = 0; jj < 4; jj++) pk[jj] = (__bf16)s0[g * 4 + jj];
            int key0 = g * 8 + 4 * b5;
            *(bf16x4*)(&Pls[wv][l31 * 64 + (key0 ^ pswz)]) = pk;
        }
#pragma unroll
        for (int g = 0; g < 4; g++) {
            bf16x4 pk;
#pragma unroll
            for (int jj = 0; jj < 4; jj++) pk[jj] = (__bf16)s1[g * 4 + jj];
            int key0 = 32 + g * 8 + 4 * b5;
            *(bf16x4*)(&Pls[wv][l31 * 64 + (key0 ^ pswz)]) = pk;
        }

        // O^T += V^T P : k-dim = keys (4 steps of 16), two d-tiles of 32
#pragma unroll
        for (int km = 0; km < 4; km++) {
            const int koff = km * 16 + b5 * 8;
            bf16x8 pf = *(const bf16x8*)(&Pls[wv][l31 * 64 + (koff ^ pswz)]);
            int d0 = l31;
            int d1 = 32 + l31;
            bf16x8 vf0 = *(const bf16x8*)(Vt + d0 * 64 + (koff ^ (((d0 ^ (d0 >> 3)) & 7) << 3)));
            bf16x8 vf1 = *(const bf16x8*)(Vt + d1 * 64 + (koff ^ (((d1 ^ (d1 >> 3)) & 7) << 3)));
            oacc0 = __builtin_amdgcn_mfma_f32_32x32x16_bf16(vf0, pf, oacc0, 0, 0, 0);
            oacc1 = __builtin_amdgcn_mfma_f32_32x32x16_bf16(vf1, pf, oacc1, 0, 0, 0);
        }
    }

    // epilogue: lane's q-row, d = dt*32 + g*8 + 4*b5 + jj
    float inv = 1.f / lsum;
    unsigned short* orow = O + ((size_t)(b * 2048 + qrow)) * 1024 + h * 64;
#pragma unroll
    for (int g = 0; g < 4; g++) {
        bf16x4 ov;
#pragma unroll
        for (int jj = 0; jj < 4; jj++) ov[jj] = (__bf16)(oacc0[g * 4 + jj] * inv);
        *(bf16x4*)(orow + g * 8 + 4 * b5) = ov;
    }
#pragma unroll
    for (int g = 0; g < 4; g++) {
        bf16x4 ov;
#pragma unroll
        for (int jj = 0; jj < 4; jj++) ov[jj] = (__bf16)(oacc1[g * 4 + jj] * inv);
        *(bf16x4*)(orow + 32 + g * 8 + 4 * b5) = ov;
    }
}

// ---------- launch ----------
extern "C" void kernel_launch(void* const* d_in, const int* in_sizes, int n_in,
                              void* d_out, int out_size, void* d_ws, size_t ws_size,
                              hipStream_t stream) {
    const float* x     = (const float*)d_in[0];
    const float* wqkv  = (const float*)d_in[1];
    const float* wproj = (const float*)d_in[2];
    float* out = (float*)d_out;

    const int BT = 4096;          // B*T
    const int DIM = 1024;
    const int NQKV = 3072;

    unsigned short* ws = (unsigned short*)d_ws;
    unsigned short* xb     = ws;
    unsigned short* wqkvb  = xb + (size_t)BT * DIM;
    unsigned short* wprojb = wqkvb + (size_t)NQKV * DIM;
    unsigned short* qb     = wprojb + (size_t)DIM * DIM;
    unsigned short* kb     = qb + (size_t)BT * DIM;
    unsigned short* vb     = kb + (size_t)BT * DIM;
    unsigned short* attb   = xb;

    cvt_all<<<(XN + WQN + WPN) / 4 / 256, 256, 0, stream>>>(x, wqkv, wproj, xb, wqkvb, wprojb);

    gemm_bt<0><<<dim3(NQKV / BN, BT / BM), 256, 0, stream>>>(xb, wqkvb, BT, NQKV, DIM,
                                                             nullptr, qb, kb, vb);
    attn_fwd<<<512, 256, 0, stream>>>(qb, kb, vb, attb);

    gemm_bt<1><<<dim3(DIM / BN, BT / BM), 256, 0, stream>>>(attb, wprojb, BT, DIM, DIM,
                                                            out, nullptr, nullptr, nullptr);
}

// Round 10
// 129.599 us; speedup vs baseline: 1.2778x; 1.2778x over previous
//
#include <hip/hip_runtime.h>
#include <hip/hip_bf16.h>
#include <stdint.h>

// ---------- types ----------
typedef __bf16 bf16x8 __attribute__((ext_vector_type(8)));
typedef __bf16 bf16x4 __attribute__((ext_vector_type(4)));
typedef float  f32x4  __attribute__((ext_vector_type(4)));
typedef float  f32x16 __attribute__((ext_vector_type(16)));

__device__ __forceinline__ unsigned short f2bf(float f) {
    unsigned u = __builtin_bit_cast(unsigned, f);
    u += 0x7fffu + ((u >> 16) & 1u);   // RNE
    return (unsigned short)(u >> 16);
}

__device__ __forceinline__ void gload16(const void* g, void* l) {
    __builtin_amdgcn_global_load_lds((const __attribute__((address_space(1))) void*)g,
                                     (__attribute__((address_space(3))) void*)l, 16, 0, 0);
}

// ---------- fused fp32 -> bf16 convert for x, w_qkv, w_proj (one launch) ----------
#define XN  4194304   // 4096*1024
#define WQN 3145728   // 3072*1024
#define WPN 1048576   // 1024*1024
__global__ void cvt_all(const float* __restrict__ x, const float* __restrict__ wq,
                        const float* __restrict__ wp,
                        unsigned short* __restrict__ xb, unsigned short* __restrict__ wqb,
                        unsigned short* __restrict__ wpb) {
    int i = (blockIdx.x * blockDim.x + threadIdx.x) * 4;
    const float* src; unsigned short* dst; int off;
    if (i < XN)            { src = x;  dst = xb;  off = i; }
    else if (i < XN + WQN) { src = wq; dst = wqb; off = i - XN; }
    else                   { src = wp; dst = wpb; off = i - XN - WQN; }
    float4 v = *(const float4*)(src + off);
    ushort4 o;
    o.x = f2bf(v.x); o.y = f2bf(v.y); o.z = f2bf(v.z); o.w = f2bf(v.w);
    *(ushort4*)(dst + off) = o;
}

// ---------- GEMM C = A * B^T  (A [M,K] row-major bf16, B [N,K] row-major bf16) ----------
// 128x128 tile, BK=64, 4 waves 2x2, global_load_lds width-16 staging, XCD-swizzled grid.
#define BM 128
#define BN 128
#define BKK 64

template<int MODE>
__global__ void gemm_bt(const unsigned short* __restrict__ A,
                        const unsigned short* __restrict__ Bm,
                        int M, int N, int K,
                        float* __restrict__ Cf,
                        unsigned short* __restrict__ Qo,
                        unsigned short* __restrict__ Ko,
                        unsigned short* __restrict__ Vo) {
    __shared__ __align__(16) unsigned short Als[BM * BKK];
    __shared__ __align__(16) unsigned short Bls[BN * BKK];

    const int tid  = threadIdx.x;
    const int lane = tid & 63;
    const int wave = tid >> 6;
    const int wm = wave >> 1, wn = wave & 1;
    // T1: XCD-aware swizzle (grid size divisible by 8 for both GEMMs)
    const int nwg = gridDim.x * gridDim.y;
    const int lid = blockIdx.y * gridDim.x + blockIdx.x;
    const int cpx = nwg >> 3;
    const int swz = (lid & 7) * cpx + (lid >> 3);
    const int m0 = (swz / gridDim.x) * BM, n0 = (swz % gridDim.x) * BN;
    const int l16 = lane & 15, lg = lane >> 4;

    f32x4 acc[4][4];
#pragma unroll
    for (int i = 0; i < 4; i++)
#pragma unroll
        for (int j = 0; j < 4; j++) acc[i][j] = f32x4{0.f, 0.f, 0.f, 0.f};

    const int r0 = tid >> 3;   // row 0..31
    const int c8 = tid & 7;    // 16B chunk

    for (int k0 = 0; k0 < K; k0 += BKK) {
        __syncthreads();
#pragma unroll
        for (int i = 0; i < 4; i++) {
            gload16(A  + (size_t)(m0 + r0 + i * 32) * K + k0 + c8 * 8,
                    Als + i * 2048 + wave * 512);
            gload16(Bm + (size_t)(n0 + r0 + i * 32) * K + k0 + c8 * 8,
                    Bls + i * 2048 + wave * 512);
        }
        __syncthreads();
#pragma unroll
        for (int ks = 0; ks < 2; ++ks) {
            const int koff = ks * 32 + lg * 8;
            bf16x8 af[4], bfv[4];
#pragma unroll
            for (int mf = 0; mf < 4; ++mf)
                af[mf] = *(const bf16x8*)(Als + (wm * 64 + mf * 16 + l16) * BKK + koff);
#pragma unroll
            for (int nf = 0; nf < 4; ++nf)
                bfv[nf] = *(const bf16x8*)(Bls + (wn * 64 + nf * 16 + l16) * BKK + koff);
#pragma unroll
            for (int mf = 0; mf < 4; ++mf)
#pragma unroll
                for (int nf = 0; nf < 4; ++nf)
                    acc[mf][nf] = __builtin_amdgcn_mfma_f32_16x16x32_bf16(af[mf], bfv[nf], acc[mf][nf], 0, 0, 0);
        }
    }

#pragma unroll
    for (int mf = 0; mf < 4; ++mf) {
        int gm = m0 + wm * 64 + mf * 16 + (lg << 2);
#pragma unroll
        for (int nf = 0; nf < 4; ++nf) {
            int gn = n0 + wn * 64 + nf * 16 + l16;
            if (MODE == 0) {
                int which = gn >> 10;
                int rem = gn & 1023;
                int h = rem >> 6, d = rem & 63;
                unsigned short* dst = (which == 0) ? Qo : (which == 1) ? Ko : Vo;
                float s = (which == 0) ? 0.180336884f : 1.0f;   // 0.125 * log2(e) for Q
#pragma unroll
                for (int j = 0; j < 4; j++) {
                    int m = gm + j;
                    int b = m >> 11, t = m & 2047;
                    dst[((size_t)((b << 4) + h) * 2048 + t) * 64 + d] = f2bf(acc[mf][nf][j] * s);
                }
            } else {
#pragma unroll
                for (int j = 0; j < 4; j++)
                    Cf[(size_t)(gm + j) * N + gn] = acc[mf][nf][j];
            }
        }
    }
}

// ---------- causal flash attention (32x32 swapped MFMA, in-register softmax) ----------
// 1D grid of 512 blocks SORTED LONGEST-FIRST: bid -> qt = 15-(bid>>5), bh = bid&31.
// QBLK=128: 4 waves x 32 q-rows. 32x32x16 MFMA halves LDS bytes per FLOP vs 16x16x32.
// __launch_bounds__(256) with NO min-waves floor: R8's (256,4) forced VGPR<=128 (spill);
// R9's no-bounds defaulted to 1024-thread assumption -> VGPR 64 (spill). (256) alone
// sets flat-work-group-size=256 and frees the allocator to ~170-230 VGPR, zero spill.
__global__ __launch_bounds__(256)
void attn_fwd(const unsigned short* __restrict__ Q,
              const unsigned short* __restrict__ Kg,
              const unsigned short* __restrict__ V,
              unsigned short* __restrict__ O) {
    __shared__ __align__(16) unsigned short Kls[64 * 64];
    __shared__ __align__(16) unsigned short Vt[64 * 64];    // [dim][key], swizzled
    __shared__ __align__(16) unsigned short Pls[4][32 * 64];

    const int tid = threadIdx.x, lane = tid & 63, wv = tid >> 6;
    const int l31 = lane & 31, b5 = lane >> 5;
    const int bid = blockIdx.x;
    const int qt = 15 - (bid >> 5);           // q-tile (128 rows), longest first
    const int bh = bid & 31;
    const size_t base = (size_t)bh * 2048 * 64;
    const unsigned short* Qp = Q + base;
    const unsigned short* Kp = Kg + base;
    const unsigned short* Vp = V + base;
    const int sr  = tid >> 3;   // staging row 0..31
    const int sc8 = tid & 7;    // staging 16B chunk
    const int b = bh >> 4, h = bh & 15;

    const int q0 = qt * 128;
    const int ntblk = 2 * qt + 2;             // KV tiles this block stages
    const int qrow = q0 + wv * 32 + l31;      // this lane's q-row
    const int qtw  = (q0 + wv * 32) >> 6;     // wave's diagonal KV-tile index
    const int pswz = ((l31 ^ (l31 >> 3)) & 7) << 3;

    // Q fragments in regs (pre-scaled by 0.125*log2e): Q[d = m*16 + b5*8 + j][q = l31]
    bf16x8 qf[4];
#pragma unroll
    for (int m = 0; m < 4; m++)
        qf[m] = *(const bf16x8*)(Qp + (size_t)qrow * 64 + m * 16 + b5 * 8);

    float mst = -INFINITY, lsum = 0.f;
    f32x16 oacc0, oacc1;
#pragma unroll
    for (int r = 0; r < 16; r++) { oacc0[r] = 0.f; oacc1[r] = 0.f; }

    // prefetch tile 0 (two 16B chunks of K and V per thread)
    uint4 kreg[2], vreg[2];
#pragma unroll
    for (int i = 0; i < 2; i++) {
        int r = sr + i * 32;
        kreg[i] = *(const uint4*)(Kp + (size_t)r * 64 + sc8 * 8);
        vreg[i] = *(const uint4*)(Vp + (size_t)r * 64 + sc8 * 8);
    }

    for (int kt = 0; kt < ntblk; ++kt) {
        __syncthreads();
#pragma unroll
        for (int i = 0; i < 2; i++) {
            int r = sr + i * 32;
            *(uint4*)(Kls + r * 64 + ((sc8 ^ (r & 7)) << 3)) = kreg[i];
            const unsigned short* pv = (const unsigned short*)&vreg[i];
#pragma unroll
            for (int j = 0; j < 8; j++) {
                int d = sc8 * 8 + j;
                Vt[d * 64 + (r ^ ((j ^ sc8) << 3))] = pv[j];
            }
        }
        __syncthreads();
        if (kt + 1 < ntblk) {
#pragma unroll
            for (int i = 0; i < 2; i++) {
                int r = sr + i * 32;
                kreg[i] = *(const uint4*)(Kp + (size_t)((kt + 1) * 64 + r) * 64 + sc8 * 8);
                vreg[i] = *(const uint4*)(Vp + (size_t)((kt + 1) * 64 + r) * 64 + sc8 * 8);
            }
        }

        if (kt > qtw) continue;   // fully masked for this wave

        // S^T = K Q^T : two key-tiles of 32, k-dim = d (4 steps of 16)
        f32x16 s0, s1;
#pragma unroll
        for (int r = 0; r < 16; r++) { s0[r] = 0.f; s1[r] = 0.f; }
#pragma unroll
        for (int m = 0; m < 4; m++) {
            const int koff = m * 16 + b5 * 8;
            int k0i = l31;
            int k1i = 32 + l31;
            bf16x8 kf0 = *(const bf16x8*)(Kls + k0i * 64 + (koff ^ ((k0i & 7) << 3)));
            bf16x8 kf1 = *(const bf16x8*)(Kls + k1i * 64 + (koff ^ ((k1i & 7) << 3)));
            s0 = __builtin_amdgcn_mfma_f32_32x32x16_bf16(kf0, qf[m], s0, 0, 0, 0);
            s1 = __builtin_amdgcn_mfma_f32_32x32x16_bf16(kf1, qf[m], s1, 0, 0, 0);
        }

        // causal mask on wave's diagonal tile
        if (kt == qtw) {
#pragma unroll
            for (int r = 0; r < 16; r++) {
                int keyg = kt * 64 + (r & 3) + 8 * (r >> 2) + 4 * b5;
                if (keyg > qrow)      s0[r] = -INFINITY;
                if (keyg + 32 > qrow) s1[r] = -INFINITY;
            }
        }

        // row max (lane-local 32 + one cross-half shfl), defer-max rescale (T13)
        float xm = fmaxf(s0[0], s1[0]);
#pragma unroll
        for (int r = 1; r < 16; r++) xm = fmaxf(xm, fmaxf(s0[r], s1[r]));
        float x = fmaxf(xm, __shfl_xor(xm, 32));
        if (!__all(x - mst <= 8.0f)) {
            float mnew  = fmaxf(mst, x);
            float alpha = __builtin_amdgcn_exp2f(mst - mnew);
            mst = mnew;
            lsum *= alpha;
#pragma unroll
            for (int r = 0; r < 16; r++) { oacc0[r] *= alpha; oacc1[r] *= alpha; }
        }

        float ra = 0.f, rb = 0.f;
#pragma unroll
        for (int r = 0; r < 16; r++) {
            s0[r] = __builtin_amdgcn_exp2f(s0[r] - mst);
            s1[r] = __builtin_amdgcn_exp2f(s1[r] - mst);
            ra += s0[r]; rb += s1[r];
        }
        float rs = ra + rb;
        rs += __shfl_xor(rs, 32);
        lsum += rs;

        // P -> LDS: row = q (l31); chunk (c*4+g), half 4*b5; swizzled by pswz
#pragma unroll
        for (int g = 0; g < 4; g++) {
            bf16x4 pk;
#pragma unroll
            for (int jj = 0; jj < 4; jj++) pk[jj] = (__bf16)s0[g * 4 + jj];
            int key0 = g * 8 + 4 * b5;
            *(bf16x4*)(&Pls[wv][l31 * 64 + (key0 ^ pswz)]) = pk;
        }
#pragma unroll
        for (int g = 0; g < 4; g++) {
            bf16x4 pk;
#pragma unroll
            for (int jj = 0; jj < 4; jj++) pk[jj] = (__bf16)s1[g * 4 + jj];
            int key0 = 32 + g * 8 + 4 * b5;
            *(bf16x4*)(&Pls[wv][l31 * 64 + (key0 ^ pswz)]) = pk;
        }

        // O^T += V^T P : k-dim = keys (4 steps of 16), two d-tiles of 32
#pragma unroll
        for (int km = 0; km < 4; km++) {
            const int koff = km * 16 + b5 * 8;
            bf16x8 pf = *(const bf16x8*)(&Pls[wv][l31 * 64 + (koff ^ pswz)]);
            int d0 = l31;
            int d1 = 32 + l31;
            bf16x8 vf0 = *(const bf16x8*)(Vt + d0 * 64 + (koff ^ (((d0 ^ (d0 >> 3)) & 7) << 3)));
            bf16x8 vf1 = *(const bf16x8*)(Vt + d1 * 64 + (koff ^ (((d1 ^ (d1 >> 3)) & 7) << 3)));
            oacc0 = __builtin_amdgcn_mfma_f32_32x32x16_bf16(vf0, pf, oacc0, 0, 0, 0);
            oacc1 = __builtin_amdgcn_mfma_f32_32x32x16_bf16(vf1, pf, oacc1, 0, 0, 0);
        }
    }

    // epilogue: lane's q-row, d = dt*32 + g*8 + 4*b5 + jj
    float inv = 1.f / lsum;
    unsigned short* orow = O + ((size_t)(b * 2048 + qrow)) * 1024 + h * 64;
#pragma unroll
    for (int g = 0; g < 4; g++) {
        bf16x4 ov;
#pragma unroll
        for (int jj = 0; jj < 4; jj++) ov[jj] = (__bf16)(oacc0[g * 4 + jj] * inv);
        *(bf16x4*)(orow + g * 8 + 4 * b5) = ov;
    }
#pragma unroll
    for (int g = 0; g < 4; g++) {
        bf16x4 ov;
#pragma unroll
        for (int jj = 0; jj < 4; jj++) ov[jj] = (__bf16)(oacc1[g * 4 + jj] * inv);
        *(bf16x4*)(orow + 32 + g * 8 + 4 * b5) = ov;
    }
}

// ---------- launch ----------
extern "C" void kernel_launch(void* const* d_in, const int* in_sizes, int n_in,
                              void* d_out, int out_size, void* d_ws, size_t ws_size,
                              hipStream_t stream) {
    const float* x     = (const float*)d_in[0];
    const float* wqkv  = (const float*)d_in[1];
    const float* wproj = (const float*)d_in[2];
    float* out = (float*)d_out;

    const int BT = 4096;          // B*T
    const int DIM = 1024;
    const int NQKV = 3072;

    unsigned short* ws = (unsigned short*)d_ws;
    unsigned short* xb     = ws;
    unsigned short* wqkvb  = xb + (size_t)BT * DIM;
    unsigned short* wprojb = wqkvb + (size_t)NQKV * DIM;
    unsigned short* qb     = wprojb + (size_t)DIM * DIM;
    unsigned short* kb     = qb + (size_t)BT * DIM;
    unsigned short* vb     = kb + (size_t)BT * DIM;
    unsigned short* attb   = xb;

    cvt_all<<<(XN + WQN + WPN) / 4 / 256, 256, 0, stream>>>(x, wqkv, wproj, xb, wqkvb, wprojb);

    gemm_bt<0><<<dim3(NQKV / BN, BT / BM), 256, 0, stream>>>(xb, wqkvb, BT, NQKV, DIM,
                                                             nullptr, qb, kb, vb);
    attn_fwd<<<512, 256, 0, stream>>>(qb, kb, vb, attb);

    gemm_bt<1><<<dim3(DIM / BN, BT / BM), 256, 0, stream>>>(attb, wprojb, BT, DIM, DIM,
                                                            out, nullptr, nullptr, nullptr);
}

// Round 11
// 129.403 us; speedup vs baseline: 1.2797x; 1.0015x over previous
//
#include <hip/hip_runtime.h>
#include <hip/hip_bf16.h>
#include <stdint.h>

// ---------- types ----------
typedef __bf16 bf16x8 __attribute__((ext_vector_type(8)));
typedef __bf16 bf16x4 __attribute__((ext_vector_type(4)));
typedef float  f32x4  __attribute__((ext_vector_type(4)));
typedef float  f32x16 __attribute__((ext_vector_type(16)));

__device__ __forceinline__ unsigned short f2bf(float f) {
    unsigned u = __builtin_bit_cast(unsigned, f);
    u += 0x7fffu + ((u >> 16) & 1u);   // RNE
    return (unsigned short)(u >> 16);
}

__device__ __forceinline__ void gload16(const void* g, void* l) {
    __builtin_amdgcn_global_load_lds((const __attribute__((address_space(1))) void*)g,
                                     (__attribute__((address_space(3))) void*)l, 16, 0, 0);
}

// ---------- fused fp32 -> bf16 convert for x, w_qkv, w_proj (one launch) ----------
#define XN  4194304   // 4096*1024
#define WQN 3145728   // 3072*1024
#define WPN 1048576   // 1024*1024
__global__ void cvt_all(const float* __restrict__ x, const float* __restrict__ wq,
                        const float* __restrict__ wp,
                        unsigned short* __restrict__ xb, unsigned short* __restrict__ wqb,
                        unsigned short* __restrict__ wpb) {
    int i = (blockIdx.x * blockDim.x + threadIdx.x) * 4;
    const float* src; unsigned short* dst; int off;
    if (i < XN)            { src = x;  dst = xb;  off = i; }
    else if (i < XN + WQN) { src = wq; dst = wqb; off = i - XN; }
    else                   { src = wp; dst = wpb; off = i - XN - WQN; }
    float4 v = *(const float4*)(src + off);
    ushort4 o;
    o.x = f2bf(v.x); o.y = f2bf(v.y); o.z = f2bf(v.z); o.w = f2bf(v.w);
    *(ushort4*)(dst + off) = o;
}

// ---------- GEMM C = A * B^T  (A [M,K] row-major bf16, B [N,K] row-major bf16) ----------
// 128x128 tile, BK=64, 4 waves 2x2, global_load_lds width-16 staging, XCD-swizzled grid.
#define BM 128
#define BN 128
#define BKK 64

template<int MODE>
__global__ void gemm_bt(const unsigned short* __restrict__ A,
                        const unsigned short* __restrict__ Bm,
                        int M, int N, int K,
                        float* __restrict__ Cf,
                        unsigned short* __restrict__ Qo,
                        unsigned short* __restrict__ Ko,
                        unsigned short* __restrict__ Vo) {
    __shared__ __align__(16) unsigned short Als[BM * BKK];
    __shared__ __align__(16) unsigned short Bls[BN * BKK];

    const int tid  = threadIdx.x;
    const int lane = tid & 63;
    const int wave = tid >> 6;
    const int wm = wave >> 1, wn = wave & 1;
    // T1: XCD-aware swizzle (grid size divisible by 8 for both GEMMs)
    const int nwg = gridDim.x * gridDim.y;
    const int lid = blockIdx.y * gridDim.x + blockIdx.x;
    const int cpx = nwg >> 3;
    const int swz = (lid & 7) * cpx + (lid >> 3);
    const int m0 = (swz / gridDim.x) * BM, n0 = (swz % gridDim.x) * BN;
    const int l16 = lane & 15, lg = lane >> 4;

    f32x4 acc[4][4];
#pragma unroll
    for (int i = 0; i < 4; i++)
#pragma unroll
        for (int j = 0; j < 4; j++) acc[i][j] = f32x4{0.f, 0.f, 0.f, 0.f};

    const int r0 = tid >> 3;   // row 0..31
    const int c8 = tid & 7;    // 16B chunk

    for (int k0 = 0; k0 < K; k0 += BKK) {
        __syncthreads();
#pragma unroll
        for (int i = 0; i < 4; i++) {
            gload16(A  + (size_t)(m0 + r0 + i * 32) * K + k0 + c8 * 8,
                    Als + i * 2048 + wave * 512);
            gload16(Bm + (size_t)(n0 + r0 + i * 32) * K + k0 + c8 * 8,
                    Bls + i * 2048 + wave * 512);
        }
        __syncthreads();
#pragma unroll
        for (int ks = 0; ks < 2; ++ks) {
            const int koff = ks * 32 + lg * 8;
            bf16x8 af[4], bfv[4];
#pragma unroll
            for (int mf = 0; mf < 4; ++mf)
                af[mf] = *(const bf16x8*)(Als + (wm * 64 + mf * 16 + l16) * BKK + koff);
#pragma unroll
            for (int nf = 0; nf < 4; ++nf)
                bfv[nf] = *(const bf16x8*)(Bls + (wn * 64 + nf * 16 + l16) * BKK + koff);
#pragma unroll
            for (int mf = 0; mf < 4; ++mf)
#pragma unroll
                for (int nf = 0; nf < 4; ++nf)
                    acc[mf][nf] = __builtin_amdgcn_mfma_f32_16x16x32_bf16(af[mf], bfv[nf], acc[mf][nf], 0, 0, 0);
        }
    }

#pragma unroll
    for (int mf = 0; mf < 4; ++mf) {
        int gm = m0 + wm * 64 + mf * 16 + (lg << 2);
#pragma unroll
        for (int nf = 0; nf < 4; ++nf) {
            int gn = n0 + wn * 64 + nf * 16 + l16;
            if (MODE == 0) {
                int which = gn >> 10;
                int rem = gn & 1023;
                int h = rem >> 6, d = rem & 63;
                unsigned short* dst = (which == 0) ? Qo : (which == 1) ? Ko : Vo;
                float s = (which == 0) ? 0.180336884f : 1.0f;   // 0.125 * log2(e) for Q
#pragma unroll
                for (int j = 0; j < 4; j++) {
                    int m = gm + j;
                    int b = m >> 11, t = m & 2047;
                    dst[((size_t)((b << 4) + h) * 2048 + t) * 64 + d] = f2bf(acc[mf][nf][j] * s);
                }
            } else {
#pragma unroll
                for (int j = 0; j < 4; j++)
                    Cf[(size_t)(gm + j) * N + gn] = acc[mf][nf][j];
            }
        }
    }
}

// ---------- causal flash attention (32x32 swapped MFMA, in-register softmax) ----------
// 1D grid of 512 blocks SORTED LONGEST-FIRST: bid -> qt = 15-(bid>>5), bh = bid&31.
// QBLK=128: 4 waves x 32 q-rows. 32x32x16 MFMA halves LDS bytes per FLOP vs 16x16x32.
// __launch_bounds__(256, 1): min-waves-per-EU=1 releases the register allocator to the
// full per-wave budget (~512). R8 (256,4)->64 VGPR spill; R9 none->64; R10 (256)->108,
// still ~4MB spill. Live state needs ~170 VGPR; grid caps residency at 2 blocks/CU anyway.
__global__ __launch_bounds__(256, 1)
void attn_fwd(const unsigned short* __restrict__ Q,
              const unsigned short* __restrict__ Kg,
              const unsigned short* __restrict__ V,
              unsigned short* __restrict__ O) {
    __shared__ __align__(16) unsigned short Kls[64 * 64];
    __shared__ __align__(16) unsigned short Vt[64 * 64];    // [dim][key], swizzled
    __shared__ __align__(16) unsigned short Pls[4][32 * 64];

    const int tid = threadIdx.x, lane = tid & 63, wv = tid >> 6;
    const int l31 = lane & 31, b5 = lane >> 5;
    const int bid = blockIdx.x;
    const int qt = 15 - (bid >> 5);           // q-tile (128 rows), longest first
    const int bh = bid & 31;
    const size_t base = (size_t)bh * 2048 * 64;
    const unsigned short* Qp = Q + base;
    const unsigned short* Kp = Kg + base;
    const unsigned short* Vp = V + base;
    const int sr  = tid >> 3;   // staging row 0..31
    const int sc8 = tid & 7;    // staging 16B chunk
    const int b = bh >> 4, h = bh & 15;

    const int q0 = qt * 128;
    const int ntblk = 2 * qt + 2;             // KV tiles this block stages
    const int qrow = q0 + wv * 32 + l31;      // this lane's q-row
    const int qtw  = (q0 + wv * 32) >> 6;     // wave's diagonal KV-tile index
    const int pswz = ((l31 ^ (l31 >> 3)) & 7) << 3;

    // Q fragments in regs (pre-scaled by 0.125*log2e): Q[d = m*16 + b5*8 + j][q = l31]
    bf16x8 qf[4];
#pragma unroll
    for (int m = 0; m < 4; m++)
        qf[m] = *(const bf16x8*)(Qp + (size_t)qrow * 64 + m * 16 + b5 * 8);

    float mst = -INFINITY, lsum = 0.f;
    f32x16 oacc0, oacc1;
#pragma unroll
    for (int r = 0; r < 16; r++) { oacc0[r] = 0.f; oacc1[r] = 0.f; }

    // prefetch tile 0 (two 16B chunks of K and V per thread)
    uint4 kreg[2], vreg[2];
#pragma unroll
    for (int i = 0; i < 2; i++) {
        int r = sr + i * 32;
        kreg[i] = *(const uint4*)(Kp + (size_t)r * 64 + sc8 * 8);
        vreg[i] = *(const uint4*)(Vp + (size_t)r * 64 + sc8 * 8);
    }

    for (int kt = 0; kt < ntblk; ++kt) {
        __syncthreads();
#pragma unroll
        for (int i = 0; i < 2; i++) {
            int r = sr + i * 32;
            *(uint4*)(Kls + r * 64 + ((sc8 ^ (r & 7)) << 3)) = kreg[i];
            const unsigned short* pv = (const unsigned short*)&vreg[i];
#pragma unroll
            for (int j = 0; j < 8; j++) {
                int d = sc8 * 8 + j;
                Vt[d * 64 + (r ^ ((j ^ sc8) << 3))] = pv[j];
            }
        }
        __syncthreads();
        if (kt + 1 < ntblk) {
#pragma unroll
            for (int i = 0; i < 2; i++) {
                int r = sr + i * 32;
                kreg[i] = *(const uint4*)(Kp + (size_t)((kt + 1) * 64 + r) * 64 + sc8 * 8);
                vreg[i] = *(const uint4*)(Vp + (size_t)((kt + 1) * 64 + r) * 64 + sc8 * 8);
            }
        }

        if (kt > qtw) continue;   // fully masked for this wave

        // S^T = K Q^T : two key-tiles of 32, k-dim = d (4 steps of 16)
        f32x16 s0, s1;
#pragma unroll
        for (int r = 0; r < 16; r++) { s0[r] = 0.f; s1[r] = 0.f; }
#pragma unroll
        for (int m = 0; m < 4; m++) {
            const int koff = m * 16 + b5 * 8;
            int k0i = l31;
            int k1i = 32 + l31;
            bf16x8 kf0 = *(const bf16x8*)(Kls + k0i * 64 + (koff ^ ((k0i & 7) << 3)));
            bf16x8 kf1 = *(const bf16x8*)(Kls + k1i * 64 + (koff ^ ((k1i & 7) << 3)));
            s0 = __builtin_amdgcn_mfma_f32_32x32x16_bf16(kf0, qf[m], s0, 0, 0, 0);
            s1 = __builtin_amdgcn_mfma_f32_32x32x16_bf16(kf1, qf[m], s1, 0, 0, 0);
        }

        // causal mask on wave's diagonal tile
        if (kt == qtw) {
#pragma unroll
            for (int r = 0; r < 16; r++) {
                int keyg = kt * 64 + (r & 3) + 8 * (r >> 2) + 4 * b5;
                if (keyg > qrow)      s0[r] = -INFINITY;
                if (keyg + 32 > qrow) s1[r] = -INFINITY;
            }
        }

        // row max (lane-local 32 + one cross-half shfl), defer-max rescale (T13)
        float xm = fmaxf(s0[0], s1[0]);
#pragma unroll
        for (int r = 1; r < 16; r++) xm = fmaxf(xm, fmaxf(s0[r], s1[r]));
        float x = fmaxf(xm, __shfl_xor(xm, 32));
        if (!__all(x - mst <= 8.0f)) {
            float mnew  = fmaxf(mst, x);
            float alpha = __builtin_amdgcn_exp2f(mst - mnew);
            mst = mnew;
            lsum *= alpha;
#pragma unroll
            for (int r = 0; r < 16; r++) { oacc0[r] *= alpha; oacc1[r] *= alpha; }
        }

        float ra = 0.f, rb = 0.f;
#pragma unroll
        for (int r = 0; r < 16; r++) {
            s0[r] = __builtin_amdgcn_exp2f(s0[r] - mst);
            s1[r] = __builtin_amdgcn_exp2f(s1[r] - mst);
            ra += s0[r]; rb += s1[r];
        }
        float rs = ra + rb;
        rs += __shfl_xor(rs, 32);
        lsum += rs;

        // P -> LDS: row = q (l31); chunk (c*4+g), half 4*b5; swizzled by pswz
#pragma unroll
        for (int g = 0; g < 4; g++) {
            bf16x4 pk;
#pragma unroll
            for (int jj = 0; jj < 4; jj++) pk[jj] = (__bf16)s0[g * 4 + jj];
            int key0 = g * 8 + 4 * b5;
            *(bf16x4*)(&Pls[wv][l31 * 64 + (key0 ^ pswz)]) = pk;
        }
#pragma unroll
        for (int g = 0; g < 4; g++) {
            bf16x4 pk;
#pragma unroll
            for (int jj = 0; jj < 4; jj++) pk[jj] = (__bf16)s1[g * 4 + jj];
            int key0 = 32 + g * 8 + 4 * b5;
            *(bf16x4*)(&Pls[wv][l31 * 64 + (key0 ^ pswz)]) = pk;
        }

        // O^T += V^T P : k-dim = keys (4 steps of 16), two d-tiles of 32
#pragma unroll
        for (int km = 0; km < 4; km++) {
            const int koff = km * 16 + b5 * 8;
            bf16x8 pf = *(const bf16x8*)(&Pls[wv][l31 * 64 + (koff ^ pswz)]);
            int d0 = l31;
            int d1 = 32 + l31;
            bf16x8 vf0 = *(const bf16x8*)(Vt + d0 * 64 + (koff ^ (((d0 ^ (d0 >> 3)) & 7) << 3)));
            bf16x8 vf1 = *(const bf16x8*)(Vt + d1 * 64 + (koff ^ (((d1 ^ (d1 >> 3)) & 7) << 3)));
            oacc0 = __builtin_amdgcn_mfma_f32_32x32x16_bf16(vf0, pf, oacc0, 0, 0, 0);
            oacc1 = __builtin_amdgcn_mfma_f32_32x32x16_bf16(vf1, pf, oacc1, 0, 0, 0);
        }
    }

    // epilogue: lane's q-row, d = dt*32 + g*8 + 4*b5 + jj
    float inv = 1.f / lsum;
    unsigned short* orow = O + ((size_t)(b * 2048 + qrow)) * 1024 + h * 64;
#pragma unroll
    for (int g = 0; g < 4; g++) {
        bf16x4 ov;
#pragma unroll
        for (int jj = 0; jj < 4; jj++) ov[jj] = (__bf16)(oacc0[g * 4 + jj] * inv);
        *(bf16x4*)(orow + g * 8 + 4 * b5) = ov;
    }
#pragma unroll
    for (int g = 0; g < 4; g++) {
        bf16x4 ov;
#pragma unroll
        for (int jj = 0; jj < 4; jj++) ov[jj] = (__bf16)(oacc1[g * 4 + jj] * inv);
        *(bf16x4*)(orow + 32 + g * 8 + 4 * b5) = ov;
    }
}

// ---------- launch ----------
extern "C" void kernel_launch(void* const* d_in, const int* in_sizes, int n_in,
                              void* d_out, int out_size, void* d_ws, size_t ws_size,
                              hipStream_t stream) {
    const float* x     = (const float*)d_in[0];
    const float* wqkv  = (const float*)d_in[1];
    const float* wproj = (const float*)d_in[2];
    float* out = (float*)d_out;

    const int BT = 4096;          // B*T
    const int DIM = 1024;
    const int NQKV = 3072;

    unsigned short* ws = (unsigned short*)d_ws;
    unsigned short* xb     = ws;
    unsigned short* wqkvb  = xb + (size_t)BT * DIM;
    unsigned short* wprojb = wqkvb + (size_t)NQKV * DIM;
    unsigned short* qb     = wprojb + (size_t)DIM * DIM;
    unsigned short* kb     = qb + (size_t)BT * DIM;
    unsigned short* vb     = kb + (size_t)BT * DIM;
    unsigned short* attb   = xb;

    cvt_all<<<(XN + WQN + WPN) / 4 / 256, 256, 0, stream>>>(x, wqkv, wproj, xb, wqkvb, wprojb);

    gemm_bt<0><<<dim3(NQKV / BN, BT / BM), 256, 0, stream>>>(xb, wqkvb, BT, NQKV, DIM,
                                                             nullptr, qb, kb, vb);
    attn_fwd<<<512, 256, 0, stream>>>(qb, kb, vb, attb);

    gemm_bt<1><<<dim3(DIM / BN, BT / BM), 256, 0, stream>>>(attb, wprojb, BT, DIM, DIM,
                                                            out, nullptr, nullptr, nullptr);
}

// Round 12
// 118.731 us; speedup vs baseline: 1.3948x; 1.0899x over previous
//
#include <hip/hip_runtime.h>
#include <hip/hip_bf16.h>
#include <stdint.h>

// ---------- types ----------
typedef __bf16 bf16x8 __attribute__((ext_vector_type(8)));
typedef __bf16 bf16x4 __attribute__((ext_vector_type(4)));
typedef float  f32x4  __attribute__((ext_vector_type(4)));

__device__ __forceinline__ unsigned short f2bf(float f) {
    unsigned u = __builtin_bit_cast(unsigned, f);
    u += 0x7fffu + ((u >> 16) & 1u);   // RNE
    return (unsigned short)(u >> 16);
}

__device__ __forceinline__ void gload16(const void* g, void* l) {
    __builtin_amdgcn_global_load_lds((const __attribute__((address_space(1))) void*)g,
                                     (__attribute__((address_space(3))) void*)l, 16, 0, 0);
}

// ---------- fused fp32 -> bf16 convert for x, w_qkv, w_proj (one launch) ----------
#define XN  4194304   // 4096*1024
#define WQN 3145728   // 3072*1024
#define WPN 1048576   // 1024*1024
__global__ void cvt_all(const float* __restrict__ x, const float* __restrict__ wq,
                        const float* __restrict__ wp,
                        unsigned short* __restrict__ xb, unsigned short* __restrict__ wqb,
                        unsigned short* __restrict__ wpb) {
    int i = (blockIdx.x * blockDim.x + threadIdx.x) * 4;
    const float* src; unsigned short* dst; int off;
    if (i < XN)            { src = x;  dst = xb;  off = i; }
    else if (i < XN + WQN) { src = wq; dst = wqb; off = i - XN; }
    else                   { src = wp; dst = wpb; off = i - XN - WQN; }
    float4 v = *(const float4*)(src + off);
    ushort4 o;
    o.x = f2bf(v.x); o.y = f2bf(v.y); o.z = f2bf(v.z); o.w = f2bf(v.w);
    *(ushort4*)(dst + off) = o;
}

// ======================================================================
// GEMM1: QKV projection, 8-phase 256x256 tile (T2+T3+T4+T5).
// C = A * B^T, A=[4096,1024] bf16, B=[3072,1024] bf16, scatter to Q/K/V.
// 512 thr = 8 waves (2M x 4N); wave out 128x64 (8x4 frags); BK=64; 2 K-tiles/iter.
// LDS 128KB: As[2][256*64] + Bs[2][256*64], chunk-XOR swizzle (c8 ^= row&7) applied
// via inverse-swizzled GLOBAL source + swizzled ds_read (linear gload_lds dest).
// Counted vmcnt(4) at phases 4/8 only; raw s_barrier; lgkmcnt(0)+sched_barrier
// per phase (rule 18); setprio(1) around MFMA clusters (T5).
// ======================================================================
#define PH_MID() do { \
    __builtin_amdgcn_s_barrier(); \
    asm volatile("s_waitcnt lgkmcnt(0)" ::: "memory"); \
    __builtin_amdgcn_sched_barrier(0); \
    __builtin_amdgcn_s_setprio(1); \
} while (0)

#define PH_END() do { \
    __builtin_amdgcn_s_setprio(0); \
    __builtin_amdgcn_sched_barrier(0); \
    __builtin_amdgcn_s_barrier(); \
} while (0)

#define PH_END_V() do { \
    __builtin_amdgcn_s_setprio(0); \
    __builtin_amdgcn_sched_barrier(0); \
    asm volatile("s_waitcnt vmcnt(4)" ::: "memory"); \
    __builtin_amdgcn_s_barrier(); \
} while (0)

__global__ __launch_bounds__(512, 1)
void gemm_qkv_8ph(const unsigned short* __restrict__ Ag,
                  const unsigned short* __restrict__ Bg,
                  unsigned short* __restrict__ Qo,
                  unsigned short* __restrict__ Ko,
                  unsigned short* __restrict__ Vo) {
    __shared__ __align__(16) unsigned short As[2][256 * 64];
    __shared__ __align__(16) unsigned short Bs[2][256 * 64];

    const int tid = threadIdx.x, lane = tid & 63;
    const int wv = tid >> 6;
    const int wm = wv >> 2, wn = wv & 3;          // 2 x 4 wave grid
    const int l16 = lane & 15, lg = lane >> 4;    // frag col, k-group
    const int sr8 = tid >> 3;                     // staging row unit 0..63
    const int sc8 = tid & 7;                      // staging chunk
    const int csw = ((sc8 ^ (sr8 & 7)) << 3);     // inverse-swizzled source chunk (shorts)
    const int ldst = sr8 * 64 + sc8 * 8;          // lane-linear LDS dest (shorts)

    // T1 XCD swizzle over 12x16 = 192 blocks (192 % 8 == 0)
    const int lid = blockIdx.y * 12 + blockIdx.x;
    const int swz = (lid & 7) * 24 + (lid >> 3);
    const int m0 = (swz / 12) * 256, n0 = (swz % 12) * 256;

    // stage one 128-row half-tile (2 x gload16/thread)
#define STAGE_A(buf, half, trow) do { \
    _Pragma("unroll") for (int i2 = 0; i2 < 2; ++i2) \
        gload16(Ag + (size_t)(m0 + (half)*128 + i2*64 + sr8) * 1024 + (trow)*64 + csw, \
                &As[buf][((half)*128 + i2*64)*64 + ldst]); \
} while (0)
#define STAGE_B(buf, half, trow) do { \
    _Pragma("unroll") for (int i2 = 0; i2 < 2; ++i2) \
        gload16(Bg + (size_t)(n0 + (half)*128 + i2*64 + sr8) * 1024 + (trow)*64 + csw, \
                &Bs[buf][((half)*128 + i2*64)*64 + ldst]); \
} while (0)
    // ds-read a quadrant's A frags (4 mfrag x 2 ks) / B frags (2 nfrag x 2 ks)
#define RD_A(buf, a) do { \
    _Pragma("unroll") for (int mf = 0; mf < 4; ++mf) \
    _Pragma("unroll") for (int ks = 0; ks < 2; ++ks) \
        Af[mf][ks] = *(const bf16x8*)(&As[buf][(wm*128 + (a)*64 + mf*16 + l16)*64 \
                                               + (((ks*4 + lg) ^ (l16 & 7)) << 3)]); \
} while (0)
#define RD_B(dst, buf, nb) do { \
    _Pragma("unroll") for (int nf = 0; nf < 2; ++nf) \
    _Pragma("unroll") for (int ks = 0; ks < 2; ++ks) \
        dst[nf][ks] = *(const bf16x8*)(&Bs[buf][(wn*64 + ((nb)*2 + nf)*16 + l16)*64 \
                                                + (((ks*4 + lg) ^ (l16 & 7)) << 3)]); \
} while (0)
#define MM(a, nb, Bf) do { \
    _Pragma("unroll") for (int ks = 0; ks < 2; ++ks) \
    _Pragma("unroll") for (int mf = 0; mf < 4; ++mf) \
    _Pragma("unroll") for (int nf = 0; nf < 2; ++nf) \
        acc[(a)*4 + mf][(nb)*2 + nf] = __builtin_amdgcn_mfma_f32_16x16x32_bf16( \
            Af[mf][ks], Bf[nf][ks], acc[(a)*4 + mf][(nb)*2 + nf], 0, 0, 0); \
} while (0)

    f32x4 acc[8][4];
#pragma unroll
    for (int i = 0; i < 8; ++i)
#pragma unroll
        for (int j = 0; j < 4; ++j) acc[i][j] = f32x4{0.f, 0.f, 0.f, 0.f};

    bf16x8 Af[4][2], Bf0[2][2], Bf1[2][2];

    // prologue: tile0 (buf0) fully + B halves of tile1 (buf1); leave B(1) in flight
    STAGE_B(0, 0, 0); STAGE_B(0, 1, 0);
    STAGE_A(0, 0, 0); STAGE_A(0, 1, 0);
    STAGE_B(1, 0, 1); STAGE_B(1, 1, 1);
    asm volatile("s_waitcnt vmcnt(4)" ::: "memory");
    __builtin_amdgcn_s_barrier();

    for (int i = 0; i < 8; ++i) {
        const int t0 = 2 * i;
        const int tA = (t0 + 2 < 16) ? t0 + 2 : 15;   // clamped addr, parity from t0+2 (=buf0)
        const int tB = (t0 + 3 < 16) ? t0 + 3 : 15;   // clamped addr, parity from t0+3 (=buf1)
        // ---- tile t0 (buf0) ----
        // p1 (a=0,b=0)
        RD_A(0, 0); RD_B(Bf0, 0, 0);
        STAGE_A(1, 0, t0 + 1);
        PH_MID(); MM(0, 0, Bf0); PH_END();
        // p2 (a=0,b=1)
        RD_B(Bf1, 0, 1);
        STAGE_A(1, 1, t0 + 1);
        PH_MID(); MM(0, 1, Bf1); PH_END();
        // p3 (a=1,b=1)
        RD_A(0, 1);
        STAGE_B(0, 0, tA);
        PH_MID(); MM(1, 1, Bf1); PH_END();
        // p4 (a=1,b=0)
        STAGE_B(0, 1, tA);
        PH_MID(); MM(1, 0, Bf0); PH_END_V();
        // ---- tile t0+1 (buf1) ----
        // p5 (a=0,b=0)
        RD_A(1, 0); RD_B(Bf0, 1, 0);
        STAGE_A(0, 0, tA);
        PH_MID(); MM(0, 0, Bf0); PH_END();
        // p6 (a=0,b=1)
        RD_B(Bf1, 1, 1);
        STAGE_A(0, 1, tA);
        PH_MID(); MM(0, 1, Bf1); PH_END();
        // p7 (a=1,b=1)
        RD_A(1, 1);
        STAGE_B(1, 0, tB);
        PH_MID(); MM(1, 1, Bf1); PH_END();
        // p8 (a=1,b=0)
        STAGE_B(1, 1, tB);
        PH_MID(); MM(1, 0, Bf0); PH_END_V();
    }

    // epilogue: scatter to Q/K/V bf16 [B,H,T,HD]; Q pre-scaled by 0.125*log2e
#pragma unroll
    for (int mf = 0; mf < 8; ++mf) {
        int gm = m0 + wm * 128 + mf * 16 + (lg << 2);
#pragma unroll
        for (int nf = 0; nf < 4; ++nf) {
            int gn = n0 + wn * 64 + nf * 16 + l16;
            int which = gn >> 10;
            int rem = gn & 1023;
            int h = rem >> 6, d = rem & 63;
            unsigned short* dst = (which == 0) ? Qo : (which == 1) ? Ko : Vo;
            float s = (which == 0) ? 0.180336884f : 1.0f;
#pragma unroll
            for (int j = 0; j < 4; j++) {
                int m = gm + j;
                int b = m >> 11, t = m & 2047;
                dst[((size_t)((b << 4) + h) * 2048 + t) * 64 + d] = f2bf(acc[mf][nf][j] * s);
            }
        }
    }
}

// ---------- GEMM2: 128x128 tile (proven structure), fp32 output ----------
#define BM 128
#define BN 128
#define BKK 64

__global__ void gemm_bt1(const unsigned short* __restrict__ A,
                         const unsigned short* __restrict__ Bm,
                         int M, int N, int K,
                         float* __restrict__ Cf) {
    __shared__ __align__(16) unsigned short Als[BM * BKK];
    __shared__ __align__(16) unsigned short Bls[BN * BKK];

    const int tid  = threadIdx.x;
    const int lane = tid & 63;
    const int wave = tid >> 6;
    const int wm = wave >> 1, wn = wave & 1;
    const int nwg = gridDim.x * gridDim.y;
    const int lid = blockIdx.y * gridDim.x + blockIdx.x;
    const int cpx = nwg >> 3;
    const int swz = (lid & 7) * cpx + (lid >> 3);
    const int m0 = (swz / gridDim.x) * BM, n0 = (swz % gridDim.x) * BN;
    const int l16 = lane & 15, lg = lane >> 4;

    f32x4 acc[4][4];
#pragma unroll
    for (int i = 0; i < 4; i++)
#pragma unroll
        for (int j = 0; j < 4; j++) acc[i][j] = f32x4{0.f, 0.f, 0.f, 0.f};

    const int r0 = tid >> 3;
    const int c8 = tid & 7;

    for (int k0 = 0; k0 < K; k0 += BKK) {
        __syncthreads();
#pragma unroll
        for (int i = 0; i < 4; i++) {
            gload16(A  + (size_t)(m0 + r0 + i * 32) * K + k0 + c8 * 8,
                    Als + i * 2048 + wave * 512);
            gload16(Bm + (size_t)(n0 + r0 + i * 32) * K + k0 + c8 * 8,
                    Bls + i * 2048 + wave * 512);
        }
        __syncthreads();
#pragma unroll
        for (int ks = 0; ks < 2; ++ks) {
            const int koff = ks * 32 + lg * 8;
            bf16x8 af[4], bfv[4];
#pragma unroll
            for (int mf = 0; mf < 4; ++mf)
                af[mf] = *(const bf16x8*)(Als + (wm * 64 + mf * 16 + l16) * BKK + koff);
#pragma unroll
            for (int nf = 0; nf < 4; ++nf)
                bfv[nf] = *(const bf16x8*)(Bls + (wn * 64 + nf * 16 + l16) * BKK + koff);
#pragma unroll
            for (int mf = 0; mf < 4; ++mf)
#pragma unroll
                for (int nf = 0; nf < 4; ++nf)
                    acc[mf][nf] = __builtin_amdgcn_mfma_f32_16x16x32_bf16(af[mf], bfv[nf], acc[mf][nf], 0, 0, 0);
        }
    }

#pragma unroll
    for (int mf = 0; mf < 4; ++mf) {
        int gm = m0 + wm * 64 + mf * 16 + (lg << 2);
#pragma unroll
        for (int nf = 0; nf < 4; ++nf) {
            int gn = n0 + wn * 64 + nf * 16 + l16;
#pragma unroll
            for (int j = 0; j < 4; j++)
                Cf[(size_t)(gm + j) * N + gn] = acc[mf][nf][j];
        }
    }
}

// ---------- causal flash attention (R7 verified: 51us, VGPR 52, no spill) ----------
// 1D grid of 512 blocks SORTED LONGEST-FIRST: bid -> qt = 15-(bid>>5), bh = bid&31.
// QBLK=128: 8 waves x 16 q-rows, all waves consume the shared KV prefix.
__global__ __launch_bounds__(512, 4)
void attn_fwd(const unsigned short* __restrict__ Q,
              const unsigned short* __restrict__ Kg,
              const unsigned short* __restrict__ V,
              unsigned short* __restrict__ O) {
    __shared__ __align__(16) unsigned short Kls[64 * 64];
    __shared__ __align__(16) unsigned short Vt[64 * 64];   // [dim][key], swizzled
    __shared__ __align__(16) unsigned short Pls[8][16 * 64];

    const int tid = threadIdx.x, lane = tid & 63, wv = tid >> 6;
    const int l16 = lane & 15, lg = lane >> 4;
    const int bid = blockIdx.x;
    const int qt = 15 - (bid >> 5);
    const int bh = bid & 31;
    const size_t base = (size_t)bh * 2048 * 64;
    const unsigned short* Qp = Q + base;
    const unsigned short* Kp = Kg + base;
    const unsigned short* Vp = V + base;
    const int sr  = tid >> 3;
    const int sc8 = tid & 7;
    const int b = bh >> 4, h = bh & 15;

    const int q0 = qt * 128;
    const int ntblk = 2 * qt + 2;
    const int qrow = q0 + wv * 16 + l16;
    const int qtw  = (q0 + wv * 16) >> 6;

    bf16x8 qf[2];
#pragma unroll
    for (int ks = 0; ks < 2; ks++)
        qf[ks] = *(const bf16x8*)(Qp + (size_t)qrow * 64 + ks * 32 + lg * 8);

    float mst = -INFINITY, lsum = 0.f;
    f32x4 oacc[4];
#pragma unroll
    for (int nf = 0; nf < 4; nf++) oacc[nf] = f32x4{0.f, 0.f, 0.f, 0.f};

    uint4 kreg, vreg;
    kreg = *(const uint4*)(Kp + (size_t)sr * 64 + sc8 * 8);
    vreg = *(const uint4*)(Vp + (size_t)sr * 64 + sc8 * 8);

    for (int kt = 0; kt < ntblk; ++kt) {
        __syncthreads();
        {
            int r = sr;
            *(uint4*)(Kls + r * 64 + ((sc8 ^ (r & 7)) << 3)) = kreg;
            const unsigned short* pv = (const unsigned short*)&vreg;
#pragma unroll
            for (int j = 0; j < 8; j++) {
                int d = sc8 * 8 + j;
                Vt[d * 64 + (r ^ ((j ^ sc8) << 3))] = pv[j];
            }
        }
        __syncthreads();
        if (kt + 1 < ntblk) {
            kreg = *(const uint4*)(Kp + (size_t)((kt + 1) * 64 + sr) * 64 + sc8 * 8);
            vreg = *(const uint4*)(Vp + (size_t)((kt + 1) * 64 + sr) * 64 + sc8 * 8);
        }

        if (kt > qtw) continue;

        f32x4 sacc[4];
#pragma unroll
        for (int nf = 0; nf < 4; nf++) sacc[nf] = f32x4{0.f, 0.f, 0.f, 0.f};
#pragma unroll
        for (int ks = 0; ks < 2; ks++) {
            const int koff = ks * 32 + lg * 8;
            bf16x8 kf[4];
#pragma unroll
            for (int nf = 0; nf < 4; nf++) {
                int key = nf * 16 + l16;
                kf[nf] = *(const bf16x8*)(Kls + key * 64 + (koff ^ ((key & 7) << 3)));
            }
#pragma unroll
            for (int nf = 0; nf < 4; nf++)
                sacc[nf] = __builtin_amdgcn_mfma_f32_16x16x32_bf16(kf[nf], qf[ks], sacc[nf], 0, 0, 0);
        }

        if (kt == qtw) {
#pragma unroll
            for (int nf = 0; nf < 4; nf++) {
                int keyb = kt * 64 + nf * 16 + (lg << 2);
#pragma unroll
                for (int j = 0; j < 4; j++)
                    if (keyb + j > qrow) sacc[nf][j] = -INFINITY;
            }
        }

        float xm[4];
#pragma unroll
        for (int nf = 0; nf < 4; nf++)
            xm[nf] = fmaxf(fmaxf(sacc[nf][0], sacc[nf][1]), fmaxf(sacc[nf][2], sacc[nf][3]));
        float x = fmaxf(fmaxf(xm[0], xm[1]), fmaxf(xm[2], xm[3]));
        x = fmaxf(x, __shfl_xor(x, 16));
        x = fmaxf(x, __shfl_xor(x, 32));
        if (!__all(x - mst <= 8.0f)) {
            float mnew  = fmaxf(mst, x);
            float alpha = __builtin_amdgcn_exp2f(mst - mnew);
            mst = mnew;
            lsum *= alpha;
#pragma unroll
            for (int nf = 0; nf < 4; nf++)
#pragma unroll
                for (int j = 0; j < 4; j++) oacc[nf][j] *= alpha;
        }
        float ps[4];
#pragma unroll
        for (int nf = 0; nf < 4; nf++) {
#pragma unroll
            for (int j = 0; j < 4; j++)
                sacc[nf][j] = __builtin_amdgcn_exp2f(sacc[nf][j] - mst);
            ps[nf] = (sacc[nf][0] + sacc[nf][1]) + (sacc[nf][2] + sacc[nf][3]);
        }
        float rs = (ps[0] + ps[1]) + (ps[2] + ps[3]);
        rs += __shfl_xor(rs, 16);
        rs += __shfl_xor(rs, 32);
        lsum += rs;

#pragma unroll
        for (int nf = 0; nf < 4; nf++) {
            bf16x4 pk;
#pragma unroll
            for (int j = 0; j < 4; j++) pk[j] = (__bf16)sacc[nf][j];
            int keyb = nf * 16 + (lg << 2);
            *(bf16x4*)(&Pls[wv][l16 * 64 + (keyb ^ ((l16 & 7) << 3))]) = pk;
        }

#pragma unroll
        for (int ks = 0; ks < 2; ks++) {
            const int koff = ks * 32 + lg * 8;
            bf16x8 pf = *(const bf16x8*)(&Pls[wv][l16 * 64 + (koff ^ ((l16 & 7) << 3))]);
            bf16x8 vf[4];
#pragma unroll
            for (int nf = 0; nf < 4; nf++) {
                int d = nf * 16 + l16;
                vf[nf] = *(const bf16x8*)(Vt + d * 64 + (koff ^ (((d & 7) ^ ((d >> 3) & 7)) << 3)));
            }
#pragma unroll
            for (int nf = 0; nf < 4; nf++)
                oacc[nf] = __builtin_amdgcn_mfma_f32_16x16x32_bf16(vf[nf], pf, oacc[nf], 0, 0, 0);
        }
    }

    {
        float inv = 1.f / lsum;
        unsigned short* orow = O + ((size_t)(b * 2048 + qrow)) * 1024 + h * 64;
#pragma unroll
        for (int nf = 0; nf < 4; nf++) {
            bf16x4 ov;
#pragma unroll
            for (int j = 0; j < 4; j++) ov[j] = (__bf16)(oacc[nf][j] * inv);
            *(bf16x4*)(orow + nf * 16 + (lg << 2)) = ov;
        }
    }
}

// ---------- launch ----------
extern "C" void kernel_launch(void* const* d_in, const int* in_sizes, int n_in,
                              void* d_out, int out_size, void* d_ws, size_t ws_size,
                              hipStream_t stream) {
    const float* x     = (const float*)d_in[0];
    const float* wqkv  = (const float*)d_in[1];
    const float* wproj = (const float*)d_in[2];
    float* out = (float*)d_out;

    const int BT = 4096;          // B*T
    const int DIM = 1024;
    const int NQKV = 3072;

    unsigned short* ws = (unsigned short*)d_ws;
    unsigned short* xb     = ws;
    unsigned short* wqkvb  = xb + (size_t)BT * DIM;
    unsigned short* wprojb = wqkvb + (size_t)NQKV * DIM;
    unsigned short* qb     = wprojb + (size_t)DIM * DIM;
    unsigned short* kb     = qb + (size_t)BT * DIM;
    unsigned short* vb     = kb + (size_t)BT * DIM;
    unsigned short* attb   = xb;

    cvt_all<<<(XN + WQN + WPN) / 4 / 256, 256, 0, stream>>>(x, wqkv, wproj, xb, wqkvb, wprojb);

    gemm_qkv_8ph<<<dim3(12, 16), 512, 0, stream>>>(xb, wqkvb, qb, kb, vb);

    attn_fwd<<<512, 512, 0, stream>>>(qb, kb, vb, attb);

    gemm_bt1<<<dim3(DIM / BN, BT / BM), 256, 0, stream>>>(attb, wprojb, BT, DIM, DIM, out);
}